// Round 19
// baseline (204.923 us; speedup 1.0000x reference)
//
#include <hip/hip_runtime.h>
#include <cstdint>
#include <cstring>

#define M_TOK 2048   // BT*S
#define DDIM 4096
#define CDIM 1024
#define LTOT 25

typedef __bf16 bf16_t;
typedef __attribute__((ext_vector_type(8))) __bf16 bf16x8;
typedef __attribute__((ext_vector_type(4))) float f32x4;
typedef __attribute__((ext_vector_type(16))) float f32x16;
typedef __attribute__((ext_vector_type(8))) int i32x8;
typedef __attribute__((ext_vector_type(4))) unsigned int u32x4;
typedef unsigned char u8;
typedef unsigned short u16;

__device__ __forceinline__ void gload16(const void* g, void* l) {
  __builtin_amdgcn_global_load_lds(
      (const __attribute__((address_space(1))) unsigned int*)g,
      (__attribute__((address_space(3))) unsigned int*)l, 16, 0, 0);
}

__device__ __forceinline__ unsigned int pk4_fp8(float x, float y, float z, float w) {
  int r = __builtin_amdgcn_cvt_pk_fp8_f32(x, y, 0, false);
  r = __builtin_amdgcn_cvt_pk_fp8_f32(z, w, r, true);
  return (unsigned int)r;
}

__device__ __forceinline__ u8 f32_to_fp8(float x) {
  return (u8)(__builtin_amdgcn_cvt_pk_fp8_f32(x, 0.f, 0, false) & 0xff);
}

__device__ __forceinline__ float fp8_to_f32(u8 b) {
  return __builtin_amdgcn_cvt_f32_fp8((int)b, 0);
}

// e2m1 encode (RNE midpoints): mags {0,.5,1,1.5,2,3,4,6}, code = sign<<3 | idx
__device__ __forceinline__ unsigned int enc_fp4(float v) {
  float a = fabsf(v);
  unsigned int q;
  if (a < 0.25f) q = 0;
  else if (a < 0.75f) q = 1;
  else if (a < 1.25f) q = 2;
  else if (a < 1.75f) q = 3;
  else if (a < 2.5f)  q = 4;
  else if (a < 3.5f)  q = 5;
  else if (a < 5.0f)  q = 6;
  else q = 7;
  return q | (v < 0.f ? 8u : 0u);
}

__device__ __forceinline__ u16 pk4_fp4(float4 v) {
  return (u16)(enc_fp4(v.x) | (enc_fp4(v.y) << 4) | (enc_fp4(v.z) << 8) | (enc_fp4(v.w) << 12));
}

// ---------------- fp32 -> fp4 convert with pre-scale (small-ws path) ----------------
__global__ void cvt_fp4(const float* __restrict__ src, u8* __restrict__ dst, long n, float sc) {
  long stride = (long)gridDim.x * blockDim.x;
  for (long i = (long)blockIdx.x * blockDim.x + threadIdx.x; i * 8 < n; i += stride) {
    const float4* s4 = (const float4*)(src + i * 8);
    float4 a = s4[0], b = s4[1];
    a.x *= sc; a.y *= sc; a.z *= sc; a.w *= sc;
    b.x *= sc; b.y *= sc; b.z *= sc; b.w *= sc;
    unsigned int pk = (unsigned int)pk4_fp4(a) | ((unsigned int)pk4_fp4(b) << 16);
    *(unsigned int*)(dst + i * 4) = pk;
  }
}

// ---------------- fp32 -> bf16 convert (owb, small-ws path) ----------------
__global__ void cvt_bf16(const float* __restrict__ src, bf16_t* __restrict__ dst, long n) {
  long stride = (long)gridDim.x * blockDim.x;
  for (long i = (long)blockIdx.x * blockDim.x + threadIdx.x; i * 8 < n; i += stride) {
    const float4* s4 = (const float4*)(src + i * 8);
    float4 a = s4[0], b = s4[1];
    bf16_t o[8] = {(bf16_t)a.x, (bf16_t)a.y, (bf16_t)a.z, (bf16_t)a.w,
                   (bf16_t)b.x, (bf16_t)b.y, (bf16_t)b.z, (bf16_t)b.w};
    uint4 pk;
    __builtin_memcpy(&pk, o, 16);
    *(uint4*)(dst + i * 8) = pk;
  }
}

// ---------------- LayerNorm + gather + fp4 convert (small-ws path) ----------------
__global__ __launch_bounds__(256)
void ln_convert(const float* __restrict__ af, const float* __restrict__ gamma,
                const float* __restrict__ beta, u8* __restrict__ xn,
                int jBase, int fuse7)
{
  int m = blockIdx.x;
  int jl = blockIdx.y;
  int j = jBase + jl;
  int layer = (j < 7) ? (24 - 4 * j) : 24;
  const float4* row4 = (const float4*)(af + ((size_t)m * LTOT + layer) * DDIM);
  int tid = threadIdx.x;
  float4 v[4];
  float s = 0.f, ss = 0.f;
#pragma unroll
  for (int i = 0; i < 4; ++i) {
    v[i] = row4[i * 256 + tid];
    s += v[i].x + v[i].y + v[i].z + v[i].w;
    ss += v[i].x * v[i].x + v[i].y * v[i].y + v[i].z * v[i].z + v[i].w * v[i].w;
  }
  int lane = tid & 63, wv = tid >> 6;
#pragma unroll
  for (int off = 32; off; off >>= 1) { s += __shfl_xor(s, off); ss += __shfl_xor(ss, off); }
  __shared__ float red[8];
  if (lane == 0) { red[wv] = s; red[4 + wv] = ss; }
  __syncthreads();
  s = red[0] + red[1] + red[2] + red[3];
  ss = red[4] + red[5] + red[6] + red[7];
  float mu = 0.f, rs = 1.f;
  if (j < 7) {
    mu = s * (1.f / DDIM);
    float var = ss * (1.f / DDIM) - mu * mu;
    rs = rsqrtf(var + 1e-5f);
  }
  const size_t rowB = DDIM / 2;   // fp4 row bytes
  if (fuse7 && jl == 0) {
    u8* o7 = xn + ((size_t)7 * M_TOK + m) * rowB;
#pragma unroll
    for (int i = 0; i < 4; ++i)
      ((u16*)o7)[i * 256 + tid] = pk4_fp4(v[i]);
  }
  u8* orow = xn + ((size_t)jl * M_TOK + m) * rowB;
  int jw = (j < 7) ? j : 0;
  const float4* g4 = (const float4*)(gamma + (size_t)jw * DDIM);
  const float4* b4 = (const float4*)(beta + (size_t)jw * DDIM);
#pragma unroll
  for (int i = 0; i < 4; ++i) {
    float4 x = v[i];
    float4 ov;
    if (j < 7) {
      float4 g = g4[i * 256 + tid], bb = b4[i * 256 + tid];
      ov.x = (x.x - mu) * rs * g.x + bb.x;
      ov.y = (x.y - mu) * rs * g.y + bb.y;
      ov.z = (x.z - mu) * rs * g.z + bb.z;
      ov.w = (x.w - mu) * rs * g.w + bb.w;
    } else ov = x;
    ((u16*)orow)[i * 256 + tid] = pk4_fp4(ov);
  }
}

// ---- fused prep: LN->fp4 slabs (y<7, slab7 in y==0) + weight cvt fp4/bf16 (y==7) ----
__global__ __launch_bounds__(256)
void prep(const float* __restrict__ af, const float* __restrict__ gamma,
          const float* __restrict__ beta, u8* __restrict__ xn,
          const float* __restrict__ norm_w, const float* __restrict__ input_w,
          const float* __restrict__ output_w, u8* __restrict__ wb4,
          bf16_t* __restrict__ owb)
{
  int tid = threadIdx.x;
  if (blockIdx.y == 7) {
    const long NW7 = (long)7 * CDIM * DDIM;
    const long NWI = (long)8 * CDIM * DDIM;
    const long TOT = NWI + (long)CDIM * CDIM;
    long stride = (long)gridDim.x * blockDim.x;
    for (long i = (long)blockIdx.x * blockDim.x + tid; i * 8 < TOT; i += stride) {
      long e = i * 8;
      const float* sp;
      if (e < NW7)      sp = norm_w + e;
      else if (e < NWI) sp = input_w + (e - NW7);
      else              sp = output_w + (e - NWI);
      const float4* s4 = (const float4*)sp;
      float4 a = s4[0], b = s4[1];
      if (e < NWI) {
        a.x *= 64.f; a.y *= 64.f; a.z *= 64.f; a.w *= 64.f;
        b.x *= 64.f; b.y *= 64.f; b.z *= 64.f; b.w *= 64.f;
        unsigned int pk = (unsigned int)pk4_fp4(a) | ((unsigned int)pk4_fp4(b) << 16);
        *(unsigned int*)(wb4 + i * 4) = pk;
      } else {
        bf16_t o[8] = {(bf16_t)a.x, (bf16_t)a.y, (bf16_t)a.z, (bf16_t)a.w,
                       (bf16_t)b.x, (bf16_t)b.y, (bf16_t)b.z, (bf16_t)b.w};
        uint4 pk;
        __builtin_memcpy(&pk, o, 16);
        *(uint4*)(owb + (e - NWI)) = pk;
      }
    }
    return;
  }
  int m = blockIdx.x;
  int jl = blockIdx.y;
  int layer = 24 - 4 * jl;
  const float4* row4 = (const float4*)(af + ((size_t)m * LTOT + layer) * DDIM);
  float4 v[4];
  float s = 0.f, ss = 0.f;
#pragma unroll
  for (int i = 0; i < 4; ++i) {
    v[i] = row4[i * 256 + tid];
    s += v[i].x + v[i].y + v[i].z + v[i].w;
    ss += v[i].x * v[i].x + v[i].y * v[i].y + v[i].z * v[i].z + v[i].w * v[i].w;
  }
  int lane = tid & 63, wv = tid >> 6;
#pragma unroll
  for (int off = 32; off; off >>= 1) { s += __shfl_xor(s, off); ss += __shfl_xor(ss, off); }
  __shared__ float red[8];
  if (lane == 0) { red[wv] = s; red[4 + wv] = ss; }
  __syncthreads();
  s = red[0] + red[1] + red[2] + red[3];
  ss = red[4] + red[5] + red[6] + red[7];
  float mu = s * (1.f / DDIM);
  float var = ss * (1.f / DDIM) - mu * mu;
  float rs = rsqrtf(var + 1e-5f);
  const size_t rowB = DDIM / 2;
  if (jl == 0) {
    u8* o7 = xn + ((size_t)7 * M_TOK + m) * rowB;
#pragma unroll
    for (int i = 0; i < 4; ++i)
      ((u16*)o7)[i * 256 + tid] = pk4_fp4(v[i]);
  }
  u8* orow = xn + ((size_t)jl * M_TOK + m) * rowB;
  const float4* g4 = (const float4*)(gamma + (size_t)jl * DDIM);
  const float4* b4 = (const float4*)(beta + (size_t)jl * DDIM);
#pragma unroll
  for (int i = 0; i < 4; ++i) {
    float4 x = v[i];
    float4 g = g4[i * 256 + tid], bb = b4[i * 256 + tid];
    float4 ov;
    ov.x = (x.x - mu) * rs * g.x + bb.x;
    ov.y = (x.y - mu) * rs * g.y + bb.y;
    ov.z = (x.z - mu) * rs * g.z + bb.z;
    ov.w = (x.w - mu) * rs * g.w + bb.w;
    ((u16*)orow)[i * 256 + tid] = pk4_fp4(ov);
  }
}

// ------ 256x256-tile MX-fp4 batched B^T GEMM: BK=256 vals (128 B/row), ring-2 ------
// (round-18-exact; see r18 comments)
__global__ __launch_bounds__(512, 2)
void gemm256mx4(const u8* __restrict__ A, const u8* __restrict__ B,
                u8* __restrict__ vo8, bf16_t* __restrict__ vinB,
                const float* __restrict__ bias,
                int Mm, int Nn, int KB, int jBase, int tilesPerJ, int tilesN)
{
  __shared__ __align__(16) u8 smem[131072];
  int nb = gridDim.x;
  int bid = blockIdx.x;
  int jl, t0;
  if (nb == tilesPerJ * 8) { jl = bid & 7; t0 = bid >> 3; }
  else { jl = bid / tilesPerJ; t0 = bid % tilesPerJ; }
  int bm = t0 / tilesN, bn = t0 % tilesN;
  int jg = jBase + jl;

  const u8* Aj = A + (size_t)jl * Mm * KB + (size_t)bm * 256 * KB;
  const u8* Bj = B + (size_t)jl * Nn * KB + (size_t)bn * 256 * KB;

  int tid = threadIdx.x;
  int lane = tid & 63, wid = tid >> 6;
  int wm = wid >> 2, wn = wid & 3;

  const u8* AsrcP[4];
  const u8* BsrcP[4];
  int AdOff[4], BdOff[4];
  int pre = ((lane & 7) ^ ((lane >> 3) & 7)) * 16;
#pragma unroll
  for (int c = 0; c < 4; ++c) {
    int S = wid * 4 + c;
    int chunk = S >> 4, s16 = S & 15;
    int row = chunk * 128 + s16 * 8 + (lane >> 3);
    AsrcP[c] = Aj + (size_t)row * KB + pre;
    BsrcP[c] = Bj + (size_t)row * KB + pre;
    AdOff[c] = chunk * 16384 + s16 * 1024;
    BdOff[c] = 32768 + chunk * 16384 + s16 * 1024;
  }

  int l31 = lane & 31;
  int lh = lane >> 5;
  int xk = l31 & 7;
  int oA[4];
#pragma unroll
  for (int s = 0; s < 4; ++s) oA[s] = ((s * 2 + lh) ^ xk) * 16;
  int aRow = l31 * 128;
  int bRowBase = (wn & 1) * 8192 + l31 * 128;
  int aChunkOff = wm * 16384;
  int bChunkOff = 32768 + (wn >> 1) * 16384;

  int NT = KB >> 7;
  f32x16 acc[4][2] = {};

#define STAGE2(tt_, bf_)                                                         \
  { _Pragma("unroll")                                                            \
    for (int c_ = 0; c_ < 4; ++c_)                                               \
      gload16(AsrcP[c_] + (size_t)(tt_) * 128, &smem[(bf_) * 65536 + AdOff[c_]]); \
    _Pragma("unroll")                                                            \
    for (int c_ = 0; c_ < 4; ++c_)                                               \
      gload16(BsrcP[c_] + (size_t)(tt_) * 128, &smem[(bf_) * 65536 + BdOff[c_]]); }

#define BAR() asm volatile("s_barrier" ::: "memory")

  STAGE2(0, 0);
  asm volatile("s_waitcnt vmcnt(0)" ::: "memory");
  BAR();

#pragma unroll 1
  for (int t = 0; t < NT; ++t) {
    int bf = t & 1;
    if (t + 1 < NT) STAGE2(t + 1, bf ^ 1);
    const u8* Ac = &smem[bf * 65536 + aChunkOff];
    const u8* Bc = &smem[bf * 65536 + bChunkOff];
#pragma unroll
    for (int s = 0; s < 4; ++s) {
      i32x8 Afr[4], Bfr[2];
#pragma unroll
      for (int ib = 0; ib < 4; ++ib) {
        u32x4 w = *(const u32x4*)(Ac + ib * 4096 + aRow + oA[s]);
        Afr[ib][0] = w[0]; Afr[ib][1] = w[1]; Afr[ib][2] = w[2]; Afr[ib][3] = w[3];
        Afr[ib][4] = 0; Afr[ib][5] = 0; Afr[ib][6] = 0; Afr[ib][7] = 0;
      }
#pragma unroll
      for (int jb = 0; jb < 2; ++jb) {
        u32x4 w = *(const u32x4*)(Bc + bRowBase + jb * 4096 + oA[s]);
        Bfr[jb][0] = w[0]; Bfr[jb][1] = w[1]; Bfr[jb][2] = w[2]; Bfr[jb][3] = w[3];
        Bfr[jb][4] = 0; Bfr[jb][5] = 0; Bfr[jb][6] = 0; Bfr[jb][7] = 0;
      }
      __builtin_amdgcn_s_setprio(1);
#pragma unroll
      for (int ib = 0; ib < 4; ++ib)
#pragma unroll
        for (int jb = 0; jb < 2; ++jb)
          acc[ib][jb] = __builtin_amdgcn_mfma_scale_f32_32x32x64_f8f6f4(
              Afr[ib], Bfr[jb], acc[ib][jb], 4, 4, 0, 127, 0, 121);
      __builtin_amdgcn_s_setprio(0);
    }
    if (t + 1 < NT) {
      asm volatile("s_waitcnt lgkmcnt(0)" ::: "memory");
      asm volatile("s_waitcnt vmcnt(0)" ::: "memory");
      BAR();
    }
  }
#undef STAGE2
#undef BAR

  int col0 = bn * 256 + wn * 64 + l31;
  int row0 = bm * 256 + wm * 128 + lh * 4;
  if (jg == 7) {
    float bv0 = bias[col0];
    float bv1 = bias[col0 + 32];
#pragma unroll
    for (int ib = 0; ib < 4; ++ib) {
#pragma unroll
      for (int jb = 0; jb < 2; ++jb) {
        float bv = jb ? bv1 : bv0;
        int gc = col0 + jb * 32;
#pragma unroll
        for (int reg = 0; reg < 16; ++reg) {
          int gr = row0 + ib * 32 + (reg & 3) + 8 * (reg >> 2);
          vinB[(size_t)gr * Nn + gc] = (bf16_t)(acc[ib][jb][reg] + bv);
        }
      }
    }
  } else {
    u8* Cj = vo8 + (size_t)jg * Mm * Nn;
#pragma unroll
    for (int ib = 0; ib < 4; ++ib) {
#pragma unroll
      for (int jb = 0; jb < 2; ++jb) {
        int gc = col0 + jb * 32;
#pragma unroll
        for (int reg = 0; reg < 16; ++reg) {
          int gr = row0 + ib * 32 + (reg & 3) + 8 * (reg >> 2);
          Cj[(size_t)gr * Nn + gc] = f32_to_fp8(acc[ib][jb][reg]);
        }
      }
    }
  }
}

// ---------------- 128x128-tile bf16 GEMM for the output projection (vf bf16) -------
__global__ __launch_bounds__(256)
void gemm_bt_epi(const bf16_t* __restrict__ A, const bf16_t* __restrict__ B,
                 bf16_t* __restrict__ Cout, const float* __restrict__ bias,
                 const bf16_t* __restrict__ vin, int Mm, int Nn, int Kk, int tilesN)
{
  __shared__ bf16_t As[128 * 64];
  __shared__ bf16_t Bs[128 * 64];
  int bid = blockIdx.x;
  int bm = bid / tilesN, bn = bid % tilesN;
  const bf16_t* Aj = A + (size_t)bm * 128 * Kk;
  const bf16_t* Bj = B + (size_t)bn * 128 * Kk;

  int tid = threadIdx.x;
  int lane = tid & 63, wv = tid >> 6;
  int wm = wv >> 1, wn = wv & 1;

  f32x4 acc[4][4] = {};

  int srow = wv * 32 + (lane >> 3);
  int scol = (lane & 7) * 8;
  const bf16_t* Ag = Aj + (size_t)srow * Kk + scol;
  const bf16_t* Bg = Bj + (size_t)srow * Kk + scol;

  for (int kt = 0; kt < Kk; kt += 64) {
#pragma unroll
    for (int c = 0; c < 4; ++c) {
      gload16(Ag + kt + (size_t)(c * 8) * Kk, &As[(wv * 32 + c * 8) * 64]);
      gload16(Bg + kt + (size_t)(c * 8) * Kk, &Bs[(wv * 32 + c * 8) * 64]);
    }
    __syncthreads();
#pragma unroll
    for (int ks = 0; ks < 2; ++ks) {
      int ko = ks * 32 + (lane >> 4) * 8;
      bf16x8 af[4], bfr[4];
#pragma unroll
      for (int i = 0; i < 4; ++i) {
        af[i] = *(const bf16x8*)&As[(wm * 64 + i * 16 + (lane & 15)) * 64 + ko];
        bfr[i] = *(const bf16x8*)&Bs[(wn * 64 + i * 16 + (lane & 15)) * 64 + ko];
      }
#pragma unroll
      for (int i = 0; i < 4; ++i)
#pragma unroll
        for (int j2 = 0; j2 < 4; ++j2)
          acc[i][j2] = __builtin_amdgcn_mfma_f32_16x16x32_bf16(af[i], bfr[j2], acc[i][j2], 0, 0, 0);
    }
    __syncthreads();
  }

  int rowBase = bm * 128 + wm * 64 + (lane >> 4) * 4;
  int colBase = bn * 128 + wn * 64 + (lane & 15);
#pragma unroll
  for (int i = 0; i < 4; ++i) {
#pragma unroll
    for (int j2 = 0; j2 < 4; ++j2) {
      int gn = colBase + j2 * 16;
      float bv = bias[gn];
#pragma unroll
      for (int r = 0; r < 4; ++r) {
        int gm = rowBase + i * 16 + r;
        Cout[(size_t)gm * Nn + gn] = (bf16_t)(acc[i][j2][r] + bv + (float)vin[(size_t)gm * Nn + gn]);
      }
    }
  }
}

// ---------------- attention over 6 kv slabs (vo8 fp8: slab0=q, 1..6=kv) ----------------
__global__ __launch_bounds__(512)
void attn_fuse(const u8* __restrict__ vo8, bf16_t* __restrict__ fuse)
{
  int m = blockIdx.x;
  int h = threadIdx.x >> 6;
  int lane = threadIdx.x & 63;
  const size_t slab = (size_t)M_TOK * CDIM;
  const u8* base = vo8 + (size_t)m * CDIM + h * 128;
  float q0 = fp8_to_f32(base[lane]), q1 = fp8_to_f32(base[lane + 64]);
  float kv0[6], kv1[6], sc[6];
#pragma unroll
  for (int k = 0; k < 6; ++k) {
    const u8* kb = base + (size_t)(k + 1) * slab;
    kv0[k] = fp8_to_f32(kb[lane]); kv1[k] = fp8_to_f32(kb[lane + 64]);
    sc[k] = q0 * kv0[k] + q1 * kv1[k];
  }
#pragma unroll
  for (int k = 0; k < 6; ++k) {
#pragma unroll
    for (int off = 32; off; off >>= 1) sc[k] += __shfl_xor(sc[k], off);
    sc[k] *= 0.03125f;  // C^-0.5
  }
  float mx = sc[0];
#pragma unroll
  for (int k = 1; k < 6; ++k) mx = fmaxf(mx, sc[k]);
  float e[6], se = 0.f;
#pragma unroll
  for (int k = 0; k < 6; ++k) { e[k] = expf(sc[k] - mx); se += e[k]; }
  float inv = 1.f / se;
  float f0 = 0.f, f1 = 0.f;
#pragma unroll
  for (int k = 0; k < 6; ++k) { float w = e[k] * inv; f0 += w * kv0[k]; f1 += w * kv1[k]; }
  bf16_t* o = fuse + (size_t)m * CDIM + h * 128;
  o[lane] = (bf16_t)f0;
  o[lane + 64] = (bf16_t)f1;
}

// ---------------- cosine per row (vf bf16) + fused final reduce ----------------
// out[0] accumulates (1 - cos_m)/M via atomicAdd (out zeroed by memsetAsync).
__global__ __launch_bounds__(256)
void cos_row(const bf16_t* __restrict__ vf, const float* __restrict__ teacher,
             float* __restrict__ out)
{
  int m = blockIdx.x;
  int tid = threadIdx.x;
  const bf16_t* arow = vf + (size_t)m * CDIM;
  float4 b = ((const float4*)(teacher + (size_t)m * CDIM))[tid];
  bf16_t a4[4];
  *(uint2*)a4 = ((const uint2*)arow)[tid];
  float ax = (float)a4[0], ay = (float)a4[1], az = (float)a4[2], aw = (float)a4[3];
  float dot = ax * b.x + ay * b.y + az * b.z + aw * b.w;
  float na = ax * ax + ay * ay + az * az + aw * aw;
  float nb = b.x * b.x + b.y * b.y + b.z * b.z + b.w * b.w;
  int lane = tid & 63, wv = tid >> 6;
#pragma unroll
  for (int off = 32; off; off >>= 1) {
    dot += __shfl_xor(dot, off); na += __shfl_xor(na, off); nb += __shfl_xor(nb, off);
  }
  __shared__ float red[12];
  if (lane == 0) { red[wv] = dot; red[4 + wv] = na; red[8 + wv] = nb; }
  __syncthreads();
  if (tid == 0) {
    float d = red[0] + red[1] + red[2] + red[3];
    float x = red[4] + red[5] + red[6] + red[7];
    float y = red[8] + red[9] + red[10] + red[11];
    float den = fmaxf(sqrtf(x), 1e-8f) * fmaxf(sqrtf(y), 1e-8f);
    atomicAdd(out, (1.f - d / den) * (1.f / M_TOK));
  }
}

extern "C" void kernel_launch(void* const* d_in, const int* in_sizes, int n_in,
                              void* d_out, int out_size, void* d_ws, size_t ws_size,
                              hipStream_t stream)
{
  (void)in_sizes; (void)n_in; (void)out_size;
  const float* all_features = (const float*)d_in[0];
  const float* teacher = (const float*)d_in[1];
  const float* ln_gamma = (const float*)d_in[2];
  const float* ln_beta = (const float*)d_in[3];
  const float* norm_w = (const float*)d_in[4];
  const float* input_w = (const float*)d_in[5];
  const float* input_b = (const float*)d_in[6];
  const float* output_w = (const float*)d_in[7];
  const float* output_b = (const float*)d_in[8];
  float* out = (float*)d_out;
  char* ws = (char*)d_ws;

  const size_t M = M_TOK, D = DDIM, C = CDIM;
  const size_t xnB = 8 * M * D / 2;      // 33.5 MB fp4 (slab7 = raw layer24)
  const size_t wbB = 8 * C * D / 2;      // 16.8 MB fp4 (x64 pre-scaled)
  const size_t owbB = C * C * 2;         // 2 MB bf16
  const size_t vo8B = 7 * M * C;         // 14.7 MB fp8 (slab0=q, 1..6=kv)
  const size_t vinB_ = M * C * 2;        // 4.2 MB bf16
  const size_t fuseB = M * C * 2;
  const size_t vfB = M * C * 2;          // bf16
  const size_t fastTotal = xnB + wbB + owbB + vo8B + vinB_ + fuseB + vfB;

  hipMemsetAsync(out, 0, sizeof(float), stream);

  if (ws_size >= fastTotal) {
    u8* xn = (u8*)ws;
    u8* wb = (u8*)(ws + xnB);
    bf16_t* owb = (bf16_t*)(ws + xnB + wbB);
    u8* vo8 = (u8*)(ws + xnB + wbB + owbB);
    bf16_t* vinp = (bf16_t*)(ws + xnB + wbB + owbB + vo8B);
    bf16_t* fuse = (bf16_t*)(ws + xnB + wbB + owbB + vo8B + vinB_);
    bf16_t* vf = (bf16_t*)(ws + xnB + wbB + owbB + vo8B + vinB_ + fuseB);

    dim3 gp((unsigned)M, 8);
    prep<<<gp, 256, 0, stream>>>(all_features, ln_gamma, ln_beta, xn,
                                 norm_w, input_w, output_w, wb, owb);
    gemm256mx4<<<256, 512, 0, stream>>>(xn, wb, vo8, vinp, input_b,
                                        (int)M, (int)C, (int)(D / 2), 0, 32, 4);
    attn_fuse<<<(unsigned)M, 512, 0, stream>>>(vo8, fuse);
    gemm_bt_epi<<<128, 256, 0, stream>>>(fuse, owb, vf, output_b, vinp,
                                         (int)M, (int)C, (int)C, 8);
    cos_row<<<(unsigned)M, 256, 0, stream>>>(vf, teacher, out);
  } else {
    // SMALL-ws fallback: loop j, reuse one xn/wb slab (fp4).
    const size_t xn1B = M * D / 2;
    const size_t wb1B = C * D / 2;
    u8* xn1 = (u8*)ws;
    u8* wb1 = (u8*)(ws + xn1B);
    bf16_t* owb = (bf16_t*)(ws + xn1B + wb1B);
    u8* vo8 = (u8*)(ws + xn1B + wb1B + owbB);
    bf16_t* vinp = (bf16_t*)(ws + xn1B + wb1B + owbB + vo8B);
    bf16_t* fuse = (bf16_t*)(ws + xn1B + wb1B + owbB + vo8B + vinB_);
    bf16_t* vf = (bf16_t*)(ws + xn1B + wb1B + owbB + vo8B + vinB_ + fuseB);

    cvt_bf16<<<512, 256, 0, stream>>>(output_w, owb, (long)(C * C));
    for (int j = 0; j < 8; ++j) {
      const float* wsrc = (j < 7) ? (norm_w + (size_t)j * C * D) : input_w;
      cvt_fp4<<<2048, 256, 0, stream>>>(wsrc, wb1, (long)(C * D), 64.f);
      dim3 g1((unsigned)M, 1);
      ln_convert<<<g1, 256, 0, stream>>>(all_features, ln_gamma, ln_beta, xn1, j, 0);
      gemm256mx4<<<32, 512, 0, stream>>>(xn1, wb1, vo8, vinp, input_b,
                                         (int)M, (int)C, (int)(D / 2), j, 32, 4);
    }
    attn_fuse<<<(unsigned)M, 512, 0, stream>>>(vo8, fuse);
    gemm_bt_epi<<<128, 256, 0, stream>>>(fuse, owb, vf, output_b, vinp,
                                         (int)M, (int)C, (int)C, 8);
    cos_row<<<(unsigned)M, 256, 0, stream>>>(vf, teacher, out);
  }
}

// Round 20
// 178.799 us; speedup vs baseline: 1.1461x; 1.1461x over previous
//
#include <hip/hip_runtime.h>
#include <cstdint>
#include <cstring>

#define M_TOK 2048   // BT*S
#define DDIM 4096
#define CDIM 1024
#define LTOT 25

typedef __bf16 bf16_t;
typedef __attribute__((ext_vector_type(8))) __bf16 bf16x8;
typedef __attribute__((ext_vector_type(4))) float f32x4;
typedef __attribute__((ext_vector_type(16))) float f32x16;
typedef __attribute__((ext_vector_type(8))) int i32x8;
typedef __attribute__((ext_vector_type(4))) unsigned int u32x4;
typedef unsigned char u8;
typedef unsigned short u16;

__device__ __forceinline__ void gload16(const void* g, void* l) {
  __builtin_amdgcn_global_load_lds(
      (const __attribute__((address_space(1))) unsigned int*)g,
      (__attribute__((address_space(3))) unsigned int*)l, 16, 0, 0);
}

__device__ __forceinline__ unsigned int pk4_fp8(float x, float y, float z, float w) {
  int r = __builtin_amdgcn_cvt_pk_fp8_f32(x, y, 0, false);
  r = __builtin_amdgcn_cvt_pk_fp8_f32(z, w, r, true);
  return (unsigned int)r;
}

__device__ __forceinline__ u8 f32_to_fp8(float x) {
  return (u8)(__builtin_amdgcn_cvt_pk_fp8_f32(x, 0.f, 0, false) & 0xff);
}

__device__ __forceinline__ float fp8_to_f32(u8 b) {
  return __builtin_amdgcn_cvt_f32_fp8((int)b, 0);
}

// e2m1 encode (RNE midpoints): mags {0,.5,1,1.5,2,3,4,6}, code = sign<<3 | idx
__device__ __forceinline__ unsigned int enc_fp4(float v) {
  float a = fabsf(v);
  unsigned int q;
  if (a < 0.25f) q = 0;
  else if (a < 0.75f) q = 1;
  else if (a < 1.25f) q = 2;
  else if (a < 1.75f) q = 3;
  else if (a < 2.5f)  q = 4;
  else if (a < 3.5f)  q = 5;
  else if (a < 5.0f)  q = 6;
  else q = 7;
  return q | (v < 0.f ? 8u : 0u);
}

__device__ __forceinline__ u16 pk4_fp4(float4 v) {
  return (u16)(enc_fp4(v.x) | (enc_fp4(v.y) << 4) | (enc_fp4(v.z) << 8) | (enc_fp4(v.w) << 12));
}

// ---------------- fp32 -> fp4 convert with pre-scale (small-ws path) ----------------
__global__ void cvt_fp4(const float* __restrict__ src, u8* __restrict__ dst, long n, float sc) {
  long stride = (long)gridDim.x * blockDim.x;
  for (long i = (long)blockIdx.x * blockDim.x + threadIdx.x; i * 8 < n; i += stride) {
    const float4* s4 = (const float4*)(src + i * 8);
    float4 a = s4[0], b = s4[1];
    a.x *= sc; a.y *= sc; a.z *= sc; a.w *= sc;
    b.x *= sc; b.y *= sc; b.z *= sc; b.w *= sc;
    unsigned int pk = (unsigned int)pk4_fp4(a) | ((unsigned int)pk4_fp4(b) << 16);
    *(unsigned int*)(dst + i * 4) = pk;
  }
}

// ---------------- fp32 -> bf16 convert (owb, small-ws path) ----------------
__global__ void cvt_bf16(const float* __restrict__ src, bf16_t* __restrict__ dst, long n) {
  long stride = (long)gridDim.x * blockDim.x;
  for (long i = (long)blockIdx.x * blockDim.x + threadIdx.x; i * 8 < n; i += stride) {
    const float4* s4 = (const float4*)(src + i * 8);
    float4 a = s4[0], b = s4[1];
    bf16_t o[8] = {(bf16_t)a.x, (bf16_t)a.y, (bf16_t)a.z, (bf16_t)a.w,
                   (bf16_t)b.x, (bf16_t)b.y, (bf16_t)b.z, (bf16_t)b.w};
    uint4 pk;
    __builtin_memcpy(&pk, o, 16);
    *(uint4*)(dst + i * 8) = pk;
  }
}

// ---------------- LayerNorm + gather + fp4 convert (small-ws path) ----------------
__global__ __launch_bounds__(256)
void ln_convert(const float* __restrict__ af, const float* __restrict__ gamma,
                const float* __restrict__ beta, u8* __restrict__ xn,
                int jBase, int fuse7)
{
  int m = blockIdx.x;
  int jl = blockIdx.y;
  int j = jBase + jl;
  int layer = (j < 7) ? (24 - 4 * j) : 24;
  const float4* row4 = (const float4*)(af + ((size_t)m * LTOT + layer) * DDIM);
  int tid = threadIdx.x;
  float4 v[4];
  float s = 0.f, ss = 0.f;
#pragma unroll
  for (int i = 0; i < 4; ++i) {
    v[i] = row4[i * 256 + tid];
    s += v[i].x + v[i].y + v[i].z + v[i].w;
    ss += v[i].x * v[i].x + v[i].y * v[i].y + v[i].z * v[i].z + v[i].w * v[i].w;
  }
  int lane = tid & 63, wv = tid >> 6;
#pragma unroll
  for (int off = 32; off; off >>= 1) { s += __shfl_xor(s, off); ss += __shfl_xor(ss, off); }
  __shared__ float red[8];
  if (lane == 0) { red[wv] = s; red[4 + wv] = ss; }
  __syncthreads();
  s = red[0] + red[1] + red[2] + red[3];
  ss = red[4] + red[5] + red[6] + red[7];
  float mu = 0.f, rs = 1.f;
  if (j < 7) {
    mu = s * (1.f / DDIM);
    float var = ss * (1.f / DDIM) - mu * mu;
    rs = rsqrtf(var + 1e-5f);
  }
  const size_t rowB = DDIM / 2;   // fp4 row bytes
  if (fuse7 && jl == 0) {
    u8* o7 = xn + ((size_t)7 * M_TOK + m) * rowB;
#pragma unroll
    for (int i = 0; i < 4; ++i)
      ((u16*)o7)[i * 256 + tid] = pk4_fp4(v[i]);
  }
  u8* orow = xn + ((size_t)jl * M_TOK + m) * rowB;
  int jw = (j < 7) ? j : 0;
  const float4* g4 = (const float4*)(gamma + (size_t)jw * DDIM);
  const float4* b4 = (const float4*)(beta + (size_t)jw * DDIM);
#pragma unroll
  for (int i = 0; i < 4; ++i) {
    float4 x = v[i];
    float4 ov;
    if (j < 7) {
      float4 g = g4[i * 256 + tid], bb = b4[i * 256 + tid];
      ov.x = (x.x - mu) * rs * g.x + bb.x;
      ov.y = (x.y - mu) * rs * g.y + bb.y;
      ov.z = (x.z - mu) * rs * g.z + bb.z;
      ov.w = (x.w - mu) * rs * g.w + bb.w;
    } else ov = x;
    ((u16*)orow)[i * 256 + tid] = pk4_fp4(ov);
  }
}

// ---- fused prep: LN->fp4 slabs (y<7, slab7 in y==0) + weight cvt fp4/bf16 (y==7) ----
__global__ __launch_bounds__(256)
void prep(const float* __restrict__ af, const float* __restrict__ gamma,
          const float* __restrict__ beta, u8* __restrict__ xn,
          const float* __restrict__ norm_w, const float* __restrict__ input_w,
          const float* __restrict__ output_w, u8* __restrict__ wb4,
          bf16_t* __restrict__ owb)
{
  int tid = threadIdx.x;
  if (blockIdx.y == 7) {
    const long NW7 = (long)7 * CDIM * DDIM;
    const long NWI = (long)8 * CDIM * DDIM;
    const long TOT = NWI + (long)CDIM * CDIM;
    long stride = (long)gridDim.x * blockDim.x;
    for (long i = (long)blockIdx.x * blockDim.x + tid; i * 8 < TOT; i += stride) {
      long e = i * 8;
      const float* sp;
      if (e < NW7)      sp = norm_w + e;
      else if (e < NWI) sp = input_w + (e - NW7);
      else              sp = output_w + (e - NWI);
      const float4* s4 = (const float4*)sp;
      float4 a = s4[0], b = s4[1];
      if (e < NWI) {
        a.x *= 64.f; a.y *= 64.f; a.z *= 64.f; a.w *= 64.f;
        b.x *= 64.f; b.y *= 64.f; b.z *= 64.f; b.w *= 64.f;
        unsigned int pk = (unsigned int)pk4_fp4(a) | ((unsigned int)pk4_fp4(b) << 16);
        *(unsigned int*)(wb4 + i * 4) = pk;
      } else {
        bf16_t o[8] = {(bf16_t)a.x, (bf16_t)a.y, (bf16_t)a.z, (bf16_t)a.w,
                       (bf16_t)b.x, (bf16_t)b.y, (bf16_t)b.z, (bf16_t)b.w};
        uint4 pk;
        __builtin_memcpy(&pk, o, 16);
        *(uint4*)(owb + (e - NWI)) = pk;
      }
    }
    return;
  }
  int m = blockIdx.x;
  int jl = blockIdx.y;
  int layer = 24 - 4 * jl;
  const float4* row4 = (const float4*)(af + ((size_t)m * LTOT + layer) * DDIM);
  float4 v[4];
  float s = 0.f, ss = 0.f;
#pragma unroll
  for (int i = 0; i < 4; ++i) {
    v[i] = row4[i * 256 + tid];
    s += v[i].x + v[i].y + v[i].z + v[i].w;
    ss += v[i].x * v[i].x + v[i].y * v[i].y + v[i].z * v[i].z + v[i].w * v[i].w;
  }
  int lane = tid & 63, wv = tid >> 6;
#pragma unroll
  for (int off = 32; off; off >>= 1) { s += __shfl_xor(s, off); ss += __shfl_xor(ss, off); }
  __shared__ float red[8];
  if (lane == 0) { red[wv] = s; red[4 + wv] = ss; }
  __syncthreads();
  s = red[0] + red[1] + red[2] + red[3];
  ss = red[4] + red[5] + red[6] + red[7];
  float mu = s * (1.f / DDIM);
  float var = ss * (1.f / DDIM) - mu * mu;
  float rs = rsqrtf(var + 1e-5f);
  const size_t rowB = DDIM / 2;
  if (jl == 0) {
    u8* o7 = xn + ((size_t)7 * M_TOK + m) * rowB;
#pragma unroll
    for (int i = 0; i < 4; ++i)
      ((u16*)o7)[i * 256 + tid] = pk4_fp4(v[i]);
  }
  u8* orow = xn + ((size_t)jl * M_TOK + m) * rowB;
  const float4* g4 = (const float4*)(gamma + (size_t)jl * DDIM);
  const float4* b4 = (const float4*)(beta + (size_t)jl * DDIM);
#pragma unroll
  for (int i = 0; i < 4; ++i) {
    float4 x = v[i];
    float4 g = g4[i * 256 + tid], bb = b4[i * 256 + tid];
    float4 ov;
    ov.x = (x.x - mu) * rs * g.x + bb.x;
    ov.y = (x.y - mu) * rs * g.y + bb.y;
    ov.z = (x.z - mu) * rs * g.z + bb.z;
    ov.w = (x.w - mu) * rs * g.w + bb.w;
    ((u16*)orow)[i * 256 + tid] = pk4_fp4(ov);
  }
}

// ------ 256x256-tile MX-fp4 batched B^T GEMM: BK=256 vals (128 B/row), ring-2 ------
// (round-18-exact; see r18 comments)
__global__ __launch_bounds__(512, 2)
void gemm256mx4(const u8* __restrict__ A, const u8* __restrict__ B,
                u8* __restrict__ vo8, bf16_t* __restrict__ vinB,
                const float* __restrict__ bias,
                int Mm, int Nn, int KB, int jBase, int tilesPerJ, int tilesN)
{
  __shared__ __align__(16) u8 smem[131072];
  int nb = gridDim.x;
  int bid = blockIdx.x;
  int jl, t0;
  if (nb == tilesPerJ * 8) { jl = bid & 7; t0 = bid >> 3; }
  else { jl = bid / tilesPerJ; t0 = bid % tilesPerJ; }
  int bm = t0 / tilesN, bn = t0 % tilesN;
  int jg = jBase + jl;

  const u8* Aj = A + (size_t)jl * Mm * KB + (size_t)bm * 256 * KB;
  const u8* Bj = B + (size_t)jl * Nn * KB + (size_t)bn * 256 * KB;

  int tid = threadIdx.x;
  int lane = tid & 63, wid = tid >> 6;
  int wm = wid >> 2, wn = wid & 3;

  const u8* AsrcP[4];
  const u8* BsrcP[4];
  int AdOff[4], BdOff[4];
  int pre = ((lane & 7) ^ ((lane >> 3) & 7)) * 16;
#pragma unroll
  for (int c = 0; c < 4; ++c) {
    int S = wid * 4 + c;
    int chunk = S >> 4, s16 = S & 15;
    int row = chunk * 128 + s16 * 8 + (lane >> 3);
    AsrcP[c] = Aj + (size_t)row * KB + pre;
    BsrcP[c] = Bj + (size_t)row * KB + pre;
    AdOff[c] = chunk * 16384 + s16 * 1024;
    BdOff[c] = 32768 + chunk * 16384 + s16 * 1024;
  }

  int l31 = lane & 31;
  int lh = lane >> 5;
  int xk = l31 & 7;
  int oA[4];
#pragma unroll
  for (int s = 0; s < 4; ++s) oA[s] = ((s * 2 + lh) ^ xk) * 16;
  int aRow = l31 * 128;
  int bRowBase = (wn & 1) * 8192 + l31 * 128;
  int aChunkOff = wm * 16384;
  int bChunkOff = 32768 + (wn >> 1) * 16384;

  int NT = KB >> 7;
  f32x16 acc[4][2] = {};

#define STAGE2(tt_, bf_)                                                         \
  { _Pragma("unroll")                                                            \
    for (int c_ = 0; c_ < 4; ++c_)                                               \
      gload16(AsrcP[c_] + (size_t)(tt_) * 128, &smem[(bf_) * 65536 + AdOff[c_]]); \
    _Pragma("unroll")                                                            \
    for (int c_ = 0; c_ < 4; ++c_)                                               \
      gload16(BsrcP[c_] + (size_t)(tt_) * 128, &smem[(bf_) * 65536 + BdOff[c_]]); }

#define BAR() asm volatile("s_barrier" ::: "memory")

  STAGE2(0, 0);
  asm volatile("s_waitcnt vmcnt(0)" ::: "memory");
  BAR();

#pragma unroll 1
  for (int t = 0; t < NT; ++t) {
    int bf = t & 1;
    if (t + 1 < NT) STAGE2(t + 1, bf ^ 1);
    const u8* Ac = &smem[bf * 65536 + aChunkOff];
    const u8* Bc = &smem[bf * 65536 + bChunkOff];
#pragma unroll
    for (int s = 0; s < 4; ++s) {
      i32x8 Afr[4], Bfr[2];
#pragma unroll
      for (int ib = 0; ib < 4; ++ib) {
        u32x4 w = *(const u32x4*)(Ac + ib * 4096 + aRow + oA[s]);
        Afr[ib][0] = w[0]; Afr[ib][1] = w[1]; Afr[ib][2] = w[2]; Afr[ib][3] = w[3];
        Afr[ib][4] = 0; Afr[ib][5] = 0; Afr[ib][6] = 0; Afr[ib][7] = 0;
      }
#pragma unroll
      for (int jb = 0; jb < 2; ++jb) {
        u32x4 w = *(const u32x4*)(Bc + bRowBase + jb * 4096 + oA[s]);
        Bfr[jb][0] = w[0]; Bfr[jb][1] = w[1]; Bfr[jb][2] = w[2]; Bfr[jb][3] = w[3];
        Bfr[jb][4] = 0; Bfr[jb][5] = 0; Bfr[jb][6] = 0; Bfr[jb][7] = 0;
      }
      __builtin_amdgcn_s_setprio(1);
#pragma unroll
      for (int ib = 0; ib < 4; ++ib)
#pragma unroll
        for (int jb = 0; jb < 2; ++jb)
          acc[ib][jb] = __builtin_amdgcn_mfma_scale_f32_32x32x64_f8f6f4(
              Afr[ib], Bfr[jb], acc[ib][jb], 4, 4, 0, 127, 0, 121);
      __builtin_amdgcn_s_setprio(0);
    }
    if (t + 1 < NT) {
      asm volatile("s_waitcnt lgkmcnt(0)" ::: "memory");
      asm volatile("s_waitcnt vmcnt(0)" ::: "memory");
      BAR();
    }
  }
#undef STAGE2
#undef BAR

  int col0 = bn * 256 + wn * 64 + l31;
  int row0 = bm * 256 + wm * 128 + lh * 4;
  if (jg == 7) {
    float bv0 = bias[col0];
    float bv1 = bias[col0 + 32];
#pragma unroll
    for (int ib = 0; ib < 4; ++ib) {
#pragma unroll
      for (int jb = 0; jb < 2; ++jb) {
        float bv = jb ? bv1 : bv0;
        int gc = col0 + jb * 32;
#pragma unroll
        for (int reg = 0; reg < 16; ++reg) {
          int gr = row0 + ib * 32 + (reg & 3) + 8 * (reg >> 2);
          vinB[(size_t)gr * Nn + gc] = (bf16_t)(acc[ib][jb][reg] + bv);
        }
      }
    }
  } else {
    u8* Cj = vo8 + (size_t)jg * Mm * Nn;
#pragma unroll
    for (int ib = 0; ib < 4; ++ib) {
#pragma unroll
      for (int jb = 0; jb < 2; ++jb) {
        int gc = col0 + jb * 32;
#pragma unroll
        for (int reg = 0; reg < 16; ++reg) {
          int gr = row0 + ib * 32 + (reg & 3) + 8 * (reg >> 2);
          Cj[(size_t)gr * Nn + gc] = f32_to_fp8(acc[ib][jb][reg]);
        }
      }
    }
  }
}

// ---------------- 128x128-tile bf16 GEMM for the output projection (vf bf16) -------
__global__ __launch_bounds__(256)
void gemm_bt_epi(const bf16_t* __restrict__ A, const bf16_t* __restrict__ B,
                 bf16_t* __restrict__ Cout, const float* __restrict__ bias,
                 const bf16_t* __restrict__ vin, int Mm, int Nn, int Kk, int tilesN)
{
  __shared__ bf16_t As[128 * 64];
  __shared__ bf16_t Bs[128 * 64];
  int bid = blockIdx.x;
  int bm = bid / tilesN, bn = bid % tilesN;
  const bf16_t* Aj = A + (size_t)bm * 128 * Kk;
  const bf16_t* Bj = B + (size_t)bn * 128 * Kk;

  int tid = threadIdx.x;
  int lane = tid & 63, wv = tid >> 6;
  int wm = wv >> 1, wn = wv & 1;

  f32x4 acc[4][4] = {};

  int srow = wv * 32 + (lane >> 3);
  int scol = (lane & 7) * 8;
  const bf16_t* Ag = Aj + (size_t)srow * Kk + scol;
  const bf16_t* Bg = Bj + (size_t)srow * Kk + scol;

  for (int kt = 0; kt < Kk; kt += 64) {
#pragma unroll
    for (int c = 0; c < 4; ++c) {
      gload16(Ag + kt + (size_t)(c * 8) * Kk, &As[(wv * 32 + c * 8) * 64]);
      gload16(Bg + kt + (size_t)(c * 8) * Kk, &Bs[(wv * 32 + c * 8) * 64]);
    }
    __syncthreads();
#pragma unroll
    for (int ks = 0; ks < 2; ++ks) {
      int ko = ks * 32 + (lane >> 4) * 8;
      bf16x8 af[4], bfr[4];
#pragma unroll
      for (int i = 0; i < 4; ++i) {
        af[i] = *(const bf16x8*)&As[(wm * 64 + i * 16 + (lane & 15)) * 64 + ko];
        bfr[i] = *(const bf16x8*)&Bs[(wn * 64 + i * 16 + (lane & 15)) * 64 + ko];
      }
#pragma unroll
      for (int i = 0; i < 4; ++i)
#pragma unroll
        for (int j2 = 0; j2 < 4; ++j2)
          acc[i][j2] = __builtin_amdgcn_mfma_f32_16x16x32_bf16(af[i], bfr[j2], acc[i][j2], 0, 0, 0);
    }
    __syncthreads();
  }

  int rowBase = bm * 128 + wm * 64 + (lane >> 4) * 4;
  int colBase = bn * 128 + wn * 64 + (lane & 15);
#pragma unroll
  for (int i = 0; i < 4; ++i) {
#pragma unroll
    for (int j2 = 0; j2 < 4; ++j2) {
      int gn = colBase + j2 * 16;
      float bv = bias[gn];
#pragma unroll
      for (int r = 0; r < 4; ++r) {
        int gm = rowBase + i * 16 + r;
        Cout[(size_t)gm * Nn + gn] = (bf16_t)(acc[i][j2][r] + bv + (float)vin[(size_t)gm * Nn + gn]);
      }
    }
  }
}

// ---------------- attention over 6 kv slabs (vo8 fp8: slab0=q, 1..6=kv) ----------------
__global__ __launch_bounds__(512)
void attn_fuse(const u8* __restrict__ vo8, bf16_t* __restrict__ fuse)
{
  int m = blockIdx.x;
  int h = threadIdx.x >> 6;
  int lane = threadIdx.x & 63;
  const size_t slab = (size_t)M_TOK * CDIM;
  const u8* base = vo8 + (size_t)m * CDIM + h * 128;
  float q0 = fp8_to_f32(base[lane]), q1 = fp8_to_f32(base[lane + 64]);
  float kv0[6], kv1[6], sc[6];
#pragma unroll
  for (int k = 0; k < 6; ++k) {
    const u8* kb = base + (size_t)(k + 1) * slab;
    kv0[k] = fp8_to_f32(kb[lane]); kv1[k] = fp8_to_f32(kb[lane + 64]);
    sc[k] = q0 * kv0[k] + q1 * kv1[k];
  }
#pragma unroll
  for (int k = 0; k < 6; ++k) {
#pragma unroll
    for (int off = 32; off; off >>= 1) sc[k] += __shfl_xor(sc[k], off);
    sc[k] *= 0.03125f;  // C^-0.5
  }
  float mx = sc[0];
#pragma unroll
  for (int k = 1; k < 6; ++k) mx = fmaxf(mx, sc[k]);
  float e[6], se = 0.f;
#pragma unroll
  for (int k = 0; k < 6; ++k) { e[k] = expf(sc[k] - mx); se += e[k]; }
  float inv = 1.f / se;
  float f0 = 0.f, f1 = 0.f;
#pragma unroll
  for (int k = 0; k < 6; ++k) { float w = e[k] * inv; f0 += w * kv0[k]; f1 += w * kv1[k]; }
  bf16_t* o = fuse + (size_t)m * CDIM + h * 128;
  o[lane] = (bf16_t)f0;
  o[lane + 64] = (bf16_t)f1;
}

// ---------------- cosine per row (vf bf16) ----------------
__global__ __launch_bounds__(256)
void cos_row(const bf16_t* __restrict__ vf, const float* __restrict__ teacher,
             float* __restrict__ cosv)
{
  int m = blockIdx.x;
  int tid = threadIdx.x;
  const bf16_t* arow = vf + (size_t)m * CDIM;
  float4 b = ((const float4*)(teacher + (size_t)m * CDIM))[tid];
  bf16_t a4[4];
  *(uint2*)a4 = ((const uint2*)arow)[tid];
  float ax = (float)a4[0], ay = (float)a4[1], az = (float)a4[2], aw = (float)a4[3];
  float dot = ax * b.x + ay * b.y + az * b.z + aw * b.w;
  float na = ax * ax + ay * ay + az * az + aw * aw;
  float nb = b.x * b.x + b.y * b.y + b.z * b.z + b.w * b.w;
  int lane = tid & 63, wv = tid >> 6;
#pragma unroll
  for (int off = 32; off; off >>= 1) {
    dot += __shfl_xor(dot, off); na += __shfl_xor(na, off); nb += __shfl_xor(nb, off);
  }
  __shared__ float red[12];
  if (lane == 0) { red[wv] = dot; red[4 + wv] = na; red[8 + wv] = nb; }
  __syncthreads();
  if (tid == 0) {
    float d = red[0] + red[1] + red[2] + red[3];
    float x = red[4] + red[5] + red[6] + red[7];
    float y = red[8] + red[9] + red[10] + red[11];
    float den = fmaxf(sqrtf(x), 1e-8f) * fmaxf(sqrtf(y), 1e-8f);
    cosv[m] = d / den;
  }
}

__global__ __launch_bounds__(256)
void final_reduce(const float* __restrict__ cosv, float* __restrict__ out)
{
  int tid = threadIdx.x;
  float s = 0.f;
  for (int i = tid; i < M_TOK; i += 256) s += cosv[i];
  int lane = tid & 63, wv = tid >> 6;
#pragma unroll
  for (int off = 32; off; off >>= 1) s += __shfl_xor(s, off);
  __shared__ float red[4];
  if (lane == 0) red[wv] = s;
  __syncthreads();
  if (tid == 0) out[0] = 1.f - (red[0] + red[1] + red[2] + red[3]) * (1.f / M_TOK);
}

extern "C" void kernel_launch(void* const* d_in, const int* in_sizes, int n_in,
                              void* d_out, int out_size, void* d_ws, size_t ws_size,
                              hipStream_t stream)
{
  (void)in_sizes; (void)n_in; (void)out_size;
  const float* all_features = (const float*)d_in[0];
  const float* teacher = (const float*)d_in[1];
  const float* ln_gamma = (const float*)d_in[2];
  const float* ln_beta = (const float*)d_in[3];
  const float* norm_w = (const float*)d_in[4];
  const float* input_w = (const float*)d_in[5];
  const float* input_b = (const float*)d_in[6];
  const float* output_w = (const float*)d_in[7];
  const float* output_b = (const float*)d_in[8];
  float* out = (float*)d_out;
  char* ws = (char*)d_ws;

  const size_t M = M_TOK, D = DDIM, C = CDIM;
  const size_t xnB = 8 * M * D / 2;      // 33.5 MB fp4 (slab7 = raw layer24)
  const size_t wbB = 8 * C * D / 2;      // 16.8 MB fp4 (x64 pre-scaled)
  const size_t owbB = C * C * 2;         // 2 MB bf16
  const size_t vo8B = 7 * M * C;         // 14.7 MB fp8 (slab0=q, 1..6=kv)
  const size_t vinB_ = M * C * 2;        // 4.2 MB bf16
  const size_t fuseB = M * C * 2;
  const size_t vfB = M * C * 2;          // bf16
  const size_t cosB = M * 4;
  const size_t fastTotal = xnB + wbB + owbB + vo8B + vinB_ + fuseB + vfB + cosB;

  if (ws_size >= fastTotal) {
    u8* xn = (u8*)ws;
    u8* wb = (u8*)(ws + xnB);
    bf16_t* owb = (bf16_t*)(ws + xnB + wbB);
    u8* vo8 = (u8*)(ws + xnB + wbB + owbB);
    bf16_t* vinp = (bf16_t*)(ws + xnB + wbB + owbB + vo8B);
    bf16_t* fuse = (bf16_t*)(ws + xnB + wbB + owbB + vo8B + vinB_);
    bf16_t* vf = (bf16_t*)(ws + xnB + wbB + owbB + vo8B + vinB_ + fuseB);
    float* cosv = (float*)(ws + xnB + wbB + owbB + vo8B + vinB_ + fuseB + vfB);

    dim3 gp((unsigned)M, 8);
    prep<<<gp, 256, 0, stream>>>(all_features, ln_gamma, ln_beta, xn,
                                 norm_w, input_w, output_w, wb, owb);
    gemm256mx4<<<256, 512, 0, stream>>>(xn, wb, vo8, vinp, input_b,
                                        (int)M, (int)C, (int)(D / 2), 0, 32, 4);
    attn_fuse<<<(unsigned)M, 512, 0, stream>>>(vo8, fuse);
    gemm_bt_epi<<<128, 256, 0, stream>>>(fuse, owb, vf, output_b, vinp,
                                         (int)M, (int)C, (int)C, 8);
    cos_row<<<(unsigned)M, 256, 0, stream>>>(vf, teacher, cosv);
    final_reduce<<<1, 256, 0, stream>>>(cosv, out);
  } else {
    // SMALL-ws fallback: loop j, reuse one xn/wb slab (fp4).
    const size_t xn1B = M * D / 2;
    const size_t wb1B = C * D / 2;
    u8* xn1 = (u8*)ws;
    u8* wb1 = (u8*)(ws + xn1B);
    bf16_t* owb = (bf16_t*)(ws + xn1B + wb1B);
    u8* vo8 = (u8*)(ws + xn1B + wb1B + owbB);
    bf16_t* vinp = (bf16_t*)(ws + xn1B + wb1B + owbB + vo8B);
    bf16_t* fuse = (bf16_t*)(ws + xn1B + wb1B + owbB + vo8B + vinB_);
    bf16_t* vf = (bf16_t*)(ws + xn1B + wb1B + owbB + vo8B + vinB_ + fuseB);
    float* cosv = (float*)(ws + xn1B + wb1B + owbB + vo8B + vinB_ + fuseB + vfB);

    cvt_bf16<<<512, 256, 0, stream>>>(output_w, owb, (long)(C * C));
    for (int j = 0; j < 8; ++j) {
      const float* wsrc = (j < 7) ? (norm_w + (size_t)j * C * D) : input_w;
      cvt_fp4<<<2048, 256, 0, stream>>>(wsrc, wb1, (long)(C * D), 64.f);
      dim3 g1((unsigned)M, 1);
      ln_convert<<<g1, 256, 0, stream>>>(all_features, ln_gamma, ln_beta, xn1, j, 0);
      gemm256mx4<<<32, 512, 0, stream>>>(xn1, wb1, vo8, vinp, input_b,
                                         (int)M, (int)C, (int)(D / 2), j, 32, 4);
    }
    attn_fuse<<<(unsigned)M, 512, 0, stream>>>(vo8, fuse);
    gemm_bt_epi<<<128, 256, 0, stream>>>(fuse, owb, vf, output_b, vinp,
                                         (int)M, (int)C, (int)C, 8);
    cos_row<<<(unsigned)M, 256, 0, stream>>>(vf, teacher, cosv);
    final_reduce<<<1, 256, 0, stream>>>(cosv, out);
  }
}